// Round 1
// baseline (481.075 us; speedup 1.0000x reference)
//
#include <hip/hip_runtime.h>
#include <hip/hip_bf16.h>

// VAE_RNN: B=4096, T=200, D=128, L=64, H=128, CIN=2L+D=256
// Persistent-block RNN: 256 blocks x 512 threads (8 waves), each block owns 16
// batch rows for all 200 steps. State y,s in LDS (fp32). ALL weights held in
// registers as bf16 MFMA B-fragments (128 VGPR/lane across 8 waves).
// time_steps input (d_in[1]) is unused by the reference.

#define NB 4096
#define NT 200
#define ND 128
#define NL 64
#define NH 128

typedef __bf16 bf16;
typedef __attribute__((ext_vector_type(8))) __bf16 bf16x8;
typedef __attribute__((ext_vector_type(4))) __bf16 bf16x4;
typedef __attribute__((ext_vector_type(4))) float f32x4;

__device__ __forceinline__ f32x4 mfma16(bf16x8 a, bf16x8 b, f32x4 c){
    return __builtin_amdgcn_mfma_f32_16x16x32_bf16(a, b, c, 0, 0, 0);
}

__device__ __forceinline__ float fast_tanh(float x){
    x = fminf(15.f, fmaxf(-15.f, x));
    float e = __expf(2.f * x);
    return (e - 1.f) * __builtin_amdgcn_rcpf(e + 1.f);
}
__device__ __forceinline__ float fast_sigmoid(float x){
    float e = __expf(-x);               // inf-safe: rcp(inf)=0, rcp(1)=1
    return __builtin_amdgcn_rcpf(1.f + e);
}

__global__ __launch_bounds__(512, 2)
void vae_rnn(const float* __restrict__ data,
             const float* __restrict__ ug_w1, const float* __restrict__ ug_b1,
             const float* __restrict__ ug_w2, const float* __restrict__ ug_b2,
             const float* __restrict__ rg_w1, const float* __restrict__ rg_b1,
             const float* __restrict__ rg_w2, const float* __restrict__ rg_b2,
             const float* __restrict__ ns_w1, const float* __restrict__ ns_b1,
             const float* __restrict__ ns_w2, const float* __restrict__ ns_b2,
             float* __restrict__ out)
{
    // bf16 activation tiles, XOR-swizzled: byte = row*stride + ((col*2) ^ ((row&7)<<4))
    __shared__ __align__(16) char h_lds [16 * 512];   // 16 x 256 bf16: [y|s|x] then [y*r|s*r|x]
    __shared__ __align__(16) char t_lds [16 * 512];   // 16 x 256 bf16: tanh(l1) of [ug|rg]
    __shared__ __align__(16) char tn_lds[16 * 256];   // 16 x 128 bf16: tanh(l1) of ns
    __shared__ float ur_lds[16][128];                 // u (cols 0..63), r (cols 64..127) fp32
    __shared__ float ys_lds[16][128];                 // y (cols 0..63), s (cols 64..127) fp32

    const int tid  = threadIdx.x;
    const int wave = tid >> 6;
    const int lane = tid & 63;
    const int lq   = lane >> 4;     // quarter-wave 0..3
    const int lc   = lane & 15;     // fragment row/col within tile
    const int row0 = blockIdx.x * 16;

    // ---------------- persistent weight fragments (bf16, registers) -------------
    // B-frag layout for mfma_f32_16x16x32_bf16: lane holds col n = lc,
    // k = kt*32 + lq*8 + e (e=0..7). Weights in memory are [K][N] row-major.

    // GEMM-A: h(16x256) @ [ug_w1|rg_w1](256x256) -> wave owns cols [32w,32w+32)
    bf16x8 wA[16]; float bA[2];
    #pragma unroll
    for (int j = 0; j < 2; ++j){
        int c = wave*32 + j*16 + lc;             // 0..255, wave-uniform branch below
        const float* W  = (c < 128) ? ug_w1 : rg_w1;
        const float* bb = (c < 128) ? ug_b1 : rg_b1;
        int n = c & 127;
        bA[j] = bb[n];
        #pragma unroll
        for (int kt = 0; kt < 8; ++kt){
            int k0 = kt*32 + lq*8;
            bf16x8 f;
            #pragma unroll
            for (int e = 0; e < 8; ++e) f[e] = (bf16)W[(k0 + e)*NH + n];
            wA[kt*2 + j] = f;
        }
    }
    // GEMM-B: t-halves(16x128) @ {ug_w2,rg_w2}(128x64) -> wave<4: u cols, wave>=4: r cols
    bf16x8 wB[4]; float bB;
    {
        const float* W  = (wave < 4) ? ug_w2 : rg_w2;
        const float* bb = (wave < 4) ? ug_b2 : rg_b2;
        int n = (wave & 3)*16 + lc;
        bB = bb[n];
        #pragma unroll
        for (int kt = 0; kt < 4; ++kt){
            int k0 = kt*32 + lq*8;
            bf16x8 f;
            #pragma unroll
            for (int e = 0; e < 8; ++e) f[e] = (bf16)W[(k0 + e)*NL + n];
            wB[kt] = f;
        }
    }
    // GEMM-C: hc(16x256) @ ns_w1(256x128) -> wave owns cols [16w,16w+16)
    bf16x8 wC[8]; float bC;
    {
        int n = wave*16 + lc;
        bC = ns_b1[n];
        #pragma unroll
        for (int kt = 0; kt < 8; ++kt){
            int k0 = kt*32 + lq*8;
            bf16x8 f;
            #pragma unroll
            for (int e = 0; e < 8; ++e) f[e] = (bf16)ns_w1[(k0 + e)*NH + n];
            wC[kt] = f;
        }
    }
    // GEMM-D: tn(16x128) @ ns_w2(128x128) -> wave owns cols [16w,16w+16)
    bf16x8 wD[4]; float bD;
    {
        int n = wave*16 + lc;
        bD = ns_b2[n];
        #pragma unroll
        for (int kt = 0; kt < 4; ++kt){
            int k0 = kt*32 + lq*8;
            bf16x8 f;
            #pragma unroll
            for (int e = 0; e < 8; ++e) f[e] = (bf16)ns_w2[(k0 + e)*NH + n];
            wD[kt] = f;
        }
    }

    // init state y=s=0
    for (int i = tid; i < 16*128; i += 512) (&ys_lds[0][0])[i] = 0.f;

    // x loader mapping: thread -> (row xr, 4 cols at xc)
    const int xr = tid >> 5;            // 0..15
    const int xc = (tid & 31) << 2;     // 0,4,...,124
    const float* xbase = data + (size_t)(row0 + xr) * (NT * ND) + xc;
    float4 xcur = *(const float4*)xbase;          // x(t=0)

    __syncthreads();

    #pragma unroll 1
    for (int t = 0; t < NT; ++t){
        // (1) h = [y | s | x]  (bf16, swizzled)
        {
            float4 yv = *(const float4*)&ys_lds[xr][xc];
            bf16x4 a = { (bf16)yv.x, (bf16)yv.y, (bf16)yv.z, (bf16)yv.w };
            *(bf16x4*)(h_lds + xr*512 + ((xc*2)        ^ ((xr&7)<<4))) = a;
            bf16x4 b = { (bf16)xcur.x, (bf16)xcur.y, (bf16)xcur.z, (bf16)xcur.w };
            *(bf16x4*)(h_lds + xr*512 + (((128+xc)*2)  ^ ((xr&7)<<4))) = b;
        }
        __syncthreads();

        // prefetch x(t+1); waitcnt lands at loop bottom -> overlaps the whole step
        float4 xnext = xcur;
        if (t + 1 < NT) xnext = *(const float4*)(xbase + (t + 1)*ND);

        // (2) t = tanh(h @ [ug_w1|rg_w1] + b1)
        {
            f32x4 a0 = {0,0,0,0}, a1 = {0,0,0,0};
            #pragma unroll
            for (int kt = 0; kt < 8; ++kt){
                int kb = kt*64 + lq*16;   // byte offset of k-slice
                bf16x8 av = *(const bf16x8*)(h_lds + lc*512 + (kb ^ ((lc&7)<<4)));
                a0 = mfma16(av, wA[kt*2+0], a0);
                a1 = mfma16(av, wA[kt*2+1], a1);
            }
            #pragma unroll
            for (int r = 0; r < 4; ++r){
                int row = lq*4 + r, sw = (row&7)<<4, c0 = wave*32 + lc;
                *(bf16*)(t_lds + row*512 + ((c0*2)      ^ sw)) = (bf16)fast_tanh(a0[r] + bA[0]);
                *(bf16*)(t_lds + row*512 + (((c0+16)*2) ^ sw)) = (bf16)fast_tanh(a1[r] + bA[1]);
            }
        }
        __syncthreads();

        // (3) u|r = sigmoid(t_half @ w2 + b2)
        {
            f32x4 a0 = {0,0,0,0};
            int off = (wave < 4) ? 0 : 256;   // byte offset: r-gate reads t cols 128..255
            #pragma unroll
            for (int kt = 0; kt < 4; ++kt){
                int kb = off + kt*64 + lq*16;
                bf16x8 av = *(const bf16x8*)(t_lds + lc*512 + (kb ^ ((lc&7)<<4)));
                a0 = mfma16(av, wB[kt], a0);
            }
            int uc = (wave < 4) ? ((wave & 3)*16 + lc) : (64 + (wave - 4)*16 + lc);
            #pragma unroll
            for (int r = 0; r < 4; ++r)
                ur_lds[lq*4 + r][uc] = fast_sigmoid(a0[r] + bB);
        }
        __syncthreads();

        // (4) hc = [y*r | s*r | x] : rewrite first 128 cols of h (x cols unchanged)
        {
            float4 yv = *(const float4*)&ys_lds[xr][xc];
            float4 rv = *(const float4*)&ur_lds[xr][64 + (xc & 63)];
            bf16x4 a = { (bf16)(yv.x*rv.x), (bf16)(yv.y*rv.y),
                         (bf16)(yv.z*rv.z), (bf16)(yv.w*rv.w) };
            *(bf16x4*)(h_lds + xr*512 + ((xc*2) ^ ((xr&7)<<4))) = a;
        }
        __syncthreads();

        // (5) tn = tanh(hc @ ns_w1 + ns_b1)
        {
            f32x4 a0 = {0,0,0,0};
            #pragma unroll
            for (int kt = 0; kt < 8; ++kt){
                int kb = kt*64 + lq*16;
                bf16x8 av = *(const bf16x8*)(h_lds + lc*512 + (kb ^ ((lc&7)<<4)));
                a0 = mfma16(av, wC[kt], a0);
            }
            #pragma unroll
            for (int r = 0; r < 4; ++r){
                int row = lq*4 + r;
                *(bf16*)(tn_lds + row*256 + (((wave*16+lc)*2) ^ ((row&7)<<4)))
                    = (bf16)fast_tanh(a0[r] + bC);
            }
        }
        __syncthreads();

        // (6) ns = tn @ ns_w2 + ns_b2 ; (7) EMA state update
        {
            f32x4 a0 = {0,0,0,0};
            #pragma unroll
            for (int kt = 0; kt < 4; ++kt){
                int kb = kt*64 + lq*16;
                bf16x8 av = *(const bf16x8*)(tn_lds + lc*256 + (kb ^ ((lc&7)<<4)));
                a0 = mfma16(av, wD[kt], a0);
            }
            int c = (wave & 3)*16 + lc;   // 0..63
            #pragma unroll
            for (int r = 0; r < 4; ++r){
                int row = lq*4 + r;
                float u = ur_lds[row][c];
                float v = a0[r] + bD;
                if (wave >= 4){           // std half
                    v = fabsf(v);
                    float so = ys_lds[row][64 + c];
                    ys_lds[row][64 + c] = (1.f - u)*v + u*so;
                } else {                  // mean half
                    float yo = ys_lds[row][c];
                    ys_lds[row][c] = (1.f - u)*v + u*yo;
                }
            }
        }
        __syncthreads();
        xcur = xnext;
    }

    // output: yT (4096x64) then sT (4096x64), fp32
    {
        float4 v = *(const float4*)&ys_lds[xr][xc];
        size_t gr = (size_t)(row0 + xr);
        if (xc < 64) *(float4*)&out[gr*64 + xc] = v;
        else         *(float4*)&out[(size_t)NB*64 + gr*64 + (xc - 64)] = v;
    }
}

extern "C" void kernel_launch(void* const* d_in, const int* in_sizes, int n_in,
                              void* d_out, int out_size, void* d_ws, size_t ws_size,
                              hipStream_t stream) {
    const float* data  = (const float*)d_in[0];
    // d_in[1] = time_steps — unused by the reference computation
    const float* ug_w1 = (const float*)d_in[2];
    const float* ug_b1 = (const float*)d_in[3];
    const float* ug_w2 = (const float*)d_in[4];
    const float* ug_b2 = (const float*)d_in[5];
    const float* rg_w1 = (const float*)d_in[6];
    const float* rg_b1 = (const float*)d_in[7];
    const float* rg_w2 = (const float*)d_in[8];
    const float* rg_b2 = (const float*)d_in[9];
    const float* ns_w1 = (const float*)d_in[10];
    const float* ns_b1 = (const float*)d_in[11];
    const float* ns_w2 = (const float*)d_in[12];
    const float* ns_b2 = (const float*)d_in[13];

    hipLaunchKernelGGL(vae_rnn, dim3(NB/16), dim3(512), 0, stream,
                       data, ug_w1, ug_b1, ug_w2, ug_b2,
                       rg_w1, rg_b1, rg_w2, rg_b2,
                       ns_w1, ns_b1, ns_w2, ns_b2,
                       (float*)d_out);
}